// Round 9
// baseline (198.598 us; speedup 1.0000x reference)
//
#include <hip/hip_runtime.h>
#include <hip/hip_bf16.h>

#define EPSBN 1e-5f

typedef short short8 __attribute__((ext_vector_type(8)));
typedef float f32x16 __attribute__((ext_vector_type(16)));

static __device__ __forceinline__ unsigned short f2u(float f){
  __hip_bfloat16 h = __float2bfloat16(f);
  union { __hip_bfloat16 h; unsigned short u; } c; c.h = h; return c.u;
}

// ---- workspace layout (bytes) ----
#define WS_G     2048
#define WS_S     7168
#define WS_T     8192
#define WS_AGGB  16384      // 147456 bf16  [b][cc2][s9][o32][ci32]
#define WS_XUP   327680     // 33554432 bf16 [b][h16(4)][r256][c256][ci16]  (plane = 1<<20 halfwords)

// ------- K1: bilinear x2 upsample -> bf16 planes [b][h16][r][c][ci16], GAP fused -------
// grid: 1024 = b(8) x h16(4) x strip(32 of 8 rows)
__global__ __launch_bounds__(256) void k_up(const float* __restrict__ x,
                                            unsigned int* __restrict__ xup32,
                                            float* __restrict__ g)
{
  __shared__ float xin[16*798];     // [ci16][ir6][j133pad]
  __shared__ float w[128];
  int tid = threadIdx.x;
  int bi  = blockIdx.x;
  int strip = bi & 31, h16 = (bi >> 5) & 3, b = bi >> 7;
  int r0 = strip * 8;
  int i0b = (int)((float)r0 * (127.0f/255.0f));

  if (tid < 128){
    int i = tid;
    float s = 0.f;
    int rstart = max(0, (int)floorf((float)(i-1)*(255.0f/127.0f)));
    #pragma unroll
    for (int k = 0; k < 8; ++k){
      int r = rstart + k;
      if (r <= 255){
        float pos = (float)r * (127.0f/255.0f);
        int i0 = (int)pos; float fr = pos - (float)i0; int i1 = min(i0+1,127);
        if (i0 == i) s += 1.0f - fr;
        if (i1 == i) s += fr;
      }
    }
    w[i] = s;
  }
  for (int e = tid; e < 12288; e += 256){
    int ir = e >> 11, rem = e & 2047, ci = rem >> 7, j = rem & 127;
    int row = min(i0b + ir, 127);
    xin[ci*798 + ir*133 + j] = x[(((size_t)(b*64 + h16*16 + ci)) << 14) + (row << 7) + j];
  }
  __syncthreads();

  // ---- GAP partial: rows 4*strip..4*strip+3 (disjoint across strips), from LDS ----
  {
    int ci_l = tid >> 4, kk = tid & 15;
    float s = 0.f;
    const float* base = &xin[ci_l*798];
    #pragma unroll
    for (int row = 0; row < 4; ++row){
      int grow = 4*strip + row;
      int ir = grow - i0b;          // in [0,5] by construction
      const float* rp = base + ir*133 + kk*8;
      float ss = 0.f;
      #pragma unroll
      for (int j = 0; j < 8; ++j) ss += rp[j]*w[kk*8+j];
      s += w[grow]*ss;
    }
    s += __shfl_down(s, 8, 16);
    s += __shfl_down(s, 4, 16);
    s += __shfl_down(s, 2, 16);
    s += __shfl_down(s, 1, 16);
    if (kk == 0) atomicAdd(&g[b*64 + h16*16 + ci_l], s*(1.0f/65536.0f));
  }

  // ---- interp phase ----
  int ci2 = tid & 7, cbase = tid >> 3;   // cbase 0..31
  int j0t[8], j1t[8]; float wwt[8];
  #pragma unroll
  for (int jj = 0; jj < 8; ++jj){
    int c = cbase + 32*jj;
    float pos = (float)c * (127.0f/255.0f);
    int j0 = (int)pos;
    j0t[jj] = j0; j1t[jj] = min(j0+1,127); wwt[jj] = pos - (float)j0;
  }
  const float* base0 = &xin[(ci2*2+0)*798];
  const float* base1 = &xin[(ci2*2+1)*798];
  size_t plane32 = ((size_t)(b*4 + h16)) << 19;   // plane base in dwords

  for (int rr = 0; rr < 8; ++rr){
    int r = r0 + rr;
    float posr = (float)r * (127.0f/255.0f);
    int i0 = (int)posr; float wh = posr - (float)i0;
    int ir0 = (i0 - i0b)*133, ir1 = (min(i0+1,127) - i0b)*133;
    #pragma unroll
    for (int jj = 0; jj < 8; ++jj){
      int c = cbase + 32*jj;
      int j0 = j0t[jj], j1 = j1t[jj]; float ww = wwt[jj];
      float v00 = base0[ir0+j0], v01 = base0[ir0+j1];
      float v10 = base0[ir1+j0], v11 = base0[ir1+j1];
      float a0 = v00 + (v01-v00)*ww;
      float a1 = v10 + (v11-v10)*ww;
      float r0v = a0 + (a1-a0)*wh;
      float u00 = base1[ir0+j0], u01 = base1[ir0+j1];
      float u10 = base1[ir1+j0], u11 = base1[ir1+j1];
      float b0 = u00 + (u01-u00)*ww;
      float b1 = u10 + (u11-u10)*ww;
      float r1v = b0 + (b1-b0)*wh;
      unsigned pack = (unsigned)f2u(r0v) | (((unsigned)f2u(r1v)) << 16);
      xup32[plane32 + (size_t)(r*256 + c)*8 + ci2] = pack;
    }
  }
}

// ------- K2: attention MLP (redundant per block) + aggregated bf16 filters -------
// layout out: [b][cc2][s9][o32][ci32]
__global__ __launch_bounds__(256) void k_aggw(const float* __restrict__ g,
                      const float* __restrict__ fc_w,
                      const float* __restrict__ bga, const float* __restrict__ bba,
                      const float* __restrict__ bma, const float* __restrict__ bva,
                      const float* __restrict__ ch_w, const float* __restrict__ ch_b,
                      const float* __restrict__ fil_w, const float* __restrict__ fil_b,
                      const float* __restrict__ sp_w, const float* __restrict__ sp_b,
                      const float* __restrict__ k_w, const float* __restrict__ k_b,
                      const float* __restrict__ bn_g, const float* __restrict__ bn_b,
                      const float* __restrict__ bn_m, const float* __restrict__ bn_v,
                      const float* __restrict__ weight,
                      unsigned short* __restrict__ aggb,
                      float* __restrict__ sS, float* __restrict__ tT)
{
  __shared__ float h[8][16];
  int tid = threadIdx.x;
  if (tid < 128){
    int b = tid >> 4, a = tid & 15;
    float acc = 0.f;
    for (int c = 0; c < 64; ++c) acc += g[b*64+c] * fc_w[a*64+c];
    float v = (acc - bma[a]) * rsqrtf(bva[a] + EPSBN) * bga[a] + bba[a];
    h[b][a] = fmaxf(v, 0.f);
  }
  __syncthreads();

  int idx = blockIdx.x*256 + tid;      // < 147456
  int ci_l = idx & 31;
  int o    = (idx >> 5) & 31;
  int s    = (idx >> 10) % 9;
  int t2   = (idx >> 10) / 9;          // b*2+cc
  int cc   = t2 & 1, b = t2 >> 1;
  int ci   = cc*32 + ci_l;

  const float* hb = h[b];
  float zc = ch_b[ci], zs = sp_b[s];
  float z0 = k_b[0],  z1 = k_b[1];
  #pragma unroll
  for (int a = 0; a < 16; ++a){
    float hv = hb[a];
    zc += hv*ch_w[ci*16+a];
    zs += hv*sp_w[s*16+a];
    z0 += hv*k_w[a];
    z1 += hv*k_w[16+a];
  }
  float chv = 1.f/(1.f+expf(-zc));
  float spv = 1.f/(1.f+expf(-zs));
  float m = fmaxf(z0,z1);
  float e0 = expf(z0-m), e1 = expf(z1-m), inv = 1.f/(e0+e1);
  float ka0 = e0*inv, ka1 = e1*inv;
  float w0 = weight[(o*64+ci)*9+s];
  float w1 = weight[((32+o)*64+ci)*9+s];
  aggb[idx] = f2u(chv*spv*(ka0*w0 + ka1*w1));

  if (blockIdx.x == 0){
    int bb = tid >> 5, oo = tid & 31;
    float z = fil_b[oo];
    #pragma unroll
    for (int a = 0; a < 16; ++a) z += h[bb][a]*fil_w[oo*16+a];
    float f = 1.f/(1.f+expf(-z));
    float invs = rsqrtf(bn_v[oo] + EPSBN);
    sS[tid] = f * bn_g[oo] * invs;
    if (bb == 0) tT[oo] = bn_b[oo] - bn_m[oo]*bn_g[oo]*invs;
  }
}

// -------- K3: MFMA implicit-GEMM conv, NO LDS — operands direct from global (L1/L2) ----
// block: 16x16 output px, all 32 Cout; 4 waves x 2 acc tiles; 2 cc chunks of 32 ci.
// xup layout IS the B-fragment layout: b128 per (px, ci-half). CHK=border predication.
template<bool CHK>
static __device__ __forceinline__ void conv_body(
    const unsigned short* __restrict__ xup,
    const unsigned short* __restrict__ aggb,
    int b, int p0, int q0, int wv, int n, int kq,
    f32x16* acc)
{
  const short8 zero8 = {0,0,0,0,0,0,0,0};
  const int rp = n >> 4, qb = n & 15;
  #pragma unroll
  for (int cc = 0; cc < 2; ++cc){
    const unsigned short* ap  = aggb + (size_t)(b*2+cc)*9216 + n*32 + kq*8;
    const unsigned short* pl0 = xup + (((size_t)(b*4 + cc*2)) << 20) + kq*8;
    const unsigned short* pl1 = pl0 + (1u << 20);
    #pragma unroll
    for (int s = 0; s < 9; ++s){
      short8 a0 = *(const short8*)&ap[s*1024];
      short8 a1 = *(const short8*)&ap[s*1024 + 16];
      const int ky = s/3, kx = s%3;
      #pragma unroll
      for (int tt = 0; tt < 2; ++tt){
        int gr = p0 - 1 + 4*wv + 2*tt + rp + ky;
        int gq = q0 - 1 + qb + kx;
        short8 b0 = zero8, b1 = zero8;
        bool v = !CHK || (((unsigned)gr < 256u) && ((unsigned)gq < 256u));
        if (v){
          int off = (gr*256 + gq)*16;
          b0 = *(const short8*)&pl0[off];
          b1 = *(const short8*)&pl1[off];
        }
        acc[tt] = __builtin_amdgcn_mfma_f32_32x32x16_bf16(a0, b0, acc[tt], 0, 0, 0);
        acc[tt] = __builtin_amdgcn_mfma_f32_32x32x16_bf16(a1, b1, acc[tt], 0, 0, 0);
      }
    }
  }
}

__global__ __launch_bounds__(256) void k_conv(const unsigned short* __restrict__ xup,
                                              const unsigned short* __restrict__ aggb,
                                              const float* __restrict__ sS,
                                              const float* __restrict__ tT,
                                              float* __restrict__ out)
{
  int tid = threadIdx.x;
  int bi  = blockIdx.x;
  int b   = bi >> 8, t = bi & 255;
  int p0  = (t >> 4) * 16, q0 = (t & 15) * 16;
  int lane = tid & 63, wv = tid >> 6;
  int n  = lane & 31;
  int kq = lane >> 5;

  f32x16 acc[2];
  #pragma unroll
  for (int i = 0; i < 16; ++i){ acc[0][i] = 0.f; acc[1][i] = 0.f; }

  bool interior = (p0 != 0) && (p0 != 240) && (q0 != 0) && (q0 != 240);
  if (interior) conv_body<false>(xup, aggb, b, p0, q0, wv, n, kq, acc);
  else          conv_body<true >(xup, aggb, b, p0, q0, wv, n, kq, acc);

  // epilogue: scale/bias + GELU(exact erf), fp32 stores
  int rp = n >> 4, qb = n & 15;
  #pragma unroll
  for (int tt = 0; tt < 2; ++tt){
    int lr = 4*wv + 2*tt + rp;
    int p = p0 + lr, q = q0 + qb;
    #pragma unroll
    for (int r = 0; r < 16; ++r){
      int o = (r & 3) + 8*(r >> 2) + 4*kq;
      float sv = sS[b*32+o], tv = tT[o];
      float valv = acc[tt][r]*sv + tv;
      float gl  = 0.5f*valv*(1.f + erff(valv*0.70710678118f));
      out[(((size_t)(b*32+o)) << 16) + (p << 8) + q] = gl;
    }
  }
}

extern "C" void kernel_launch(void* const* d_in, const int* in_sizes, int n_in,
                              void* d_out, int out_size, void* d_ws, size_t ws_size,
                              hipStream_t stream)
{
  const float* x     = (const float*)d_in[0];
  const float* fc_w  = (const float*)d_in[1];
  const float* bga   = (const float*)d_in[2];
  const float* bba   = (const float*)d_in[3];
  const float* bma   = (const float*)d_in[4];
  const float* bva   = (const float*)d_in[5];
  const float* ch_w  = (const float*)d_in[6];
  const float* ch_b  = (const float*)d_in[7];
  const float* fil_w = (const float*)d_in[8];
  const float* fil_b = (const float*)d_in[9];
  const float* sp_w  = (const float*)d_in[10];
  const float* sp_b  = (const float*)d_in[11];
  const float* k_w   = (const float*)d_in[12];
  const float* k_b   = (const float*)d_in[13];
  const float* weight= (const float*)d_in[14];
  const float* bn_g  = (const float*)d_in[15];
  const float* bn_b  = (const float*)d_in[16];
  const float* bn_m  = (const float*)d_in[17];
  const float* bn_v  = (const float*)d_in[18];

  char* ws = (char*)d_ws;
  float* g   = (float*)(ws + WS_G);
  float* sS  = (float*)(ws + WS_S);
  float* tT  = (float*)(ws + WS_T);
  unsigned short* aggb = (unsigned short*)(ws + WS_AGGB);
  unsigned short* xup  = (unsigned short*)(ws + WS_XUP);
  float* out = (float*)d_out;

  hipMemsetAsync(g, 0, 512*sizeof(float), stream);
  hipLaunchKernelGGL(k_up,   dim3(1024), dim3(256), 0, stream, x, (unsigned int*)xup, g);
  hipLaunchKernelGGL(k_aggw, dim3(576),  dim3(256), 0, stream, g, fc_w, bga, bba, bma, bva,
                     ch_w, ch_b, fil_w, fil_b, sp_w, sp_b, k_w, k_b,
                     bn_g, bn_b, bn_m, bn_v, weight, aggb, sS, tT);
  hipLaunchKernelGGL(k_conv, dim3(2048), dim3(256), 0, stream, xup, aggb, sS, tT, out);
}